// Round 3
// baseline (157.863 us; speedup 1.0000x reference)
//
#include <hip/hip_runtime.h>

// MHA: x[2,2048,1024] fp32; Q/K/V/O projections (y = x@W.T + b), 16 heads x 64,
// softmax(QK^T/8)V, output projection. bf16 MFMA, fp32 accumulate.
// R3: 2-phase counted-vmcnt pipelines (raw s_barrier, no syncthreads drain),
// 8-wave QB=256 flash blocks with double-buffered K/V, exp2-folded scale,
// defer-max (THR=8), setprio around MFMA.

#define DIM 1024
#define NH 16
#define HD 64
#define SEQ 2048
#define NROWS 4096  // B*T

typedef unsigned short u16;
typedef __bf16 bf16_t;
typedef bf16_t bf16x8 __attribute__((ext_vector_type(8)));
typedef float f32x4 __attribute__((ext_vector_type(4)));
typedef u16 u16x4 __attribute__((ext_vector_type(4)));

typedef const __attribute__((address_space(1))) void* gas_ptr;
typedef __attribute__((address_space(3))) void* las_ptr;

#define S_BARRIER() asm volatile("s_barrier" ::: "memory")
#define S_WAITCNT_VM(N) asm volatile("s_waitcnt vmcnt(" #N ")" ::: "memory")

__device__ __forceinline__ void gl_lds16(const void* g, void* lds_wave_base) {
  __builtin_amdgcn_global_load_lds((gas_ptr)g, (las_ptr)lds_wave_base, 16, 0, 0);
}

__device__ __forceinline__ f32x4 mfma_bf16(bf16x8 a, bf16x8 b, f32x4 c) {
  return __builtin_amdgcn_mfma_f32_16x16x32_bf16(a, b, c, 0, 0, 0);
}

__device__ __forceinline__ u16 bfu(float f) {
  bf16_t b = (bf16_t)f;  // fptrunc, RNE
  union { bf16_t b; u16 u; } cv; cv.b = b; return cv.u;
}

#define QSCALE 0.18033688f  // log2(e)/8: folds both 1/sqrt(64) and exp->exp2

// ---------------- fp32 -> bf16 converts ----------------
__global__ void cvt_x(const float* __restrict__ in, u16* __restrict__ out) {
  int i = blockIdx.x * 256 + threadIdx.x;
  float4 v = ((const float4*)in)[i];
  u16x4 o;
  o.x = bfu(v.x); o.y = bfu(v.y); o.z = bfu(v.z); o.w = bfu(v.w);
  ((u16x4*)out)[i] = o;
}

// all four weights in one launch; Wq scaled by log2e/8 (folds QK^T scale + exp2)
__global__ void cvt_w4(const float* __restrict__ wq, const float* __restrict__ wk,
                       const float* __restrict__ wv, const float* __restrict__ wo,
                       u16* __restrict__ oq, u16* __restrict__ ok,
                       u16* __restrict__ ov, u16* __restrict__ oo) {
  const int which = blockIdx.y;
  const float* in = which == 0 ? wq : which == 1 ? wk : which == 2 ? wv : wo;
  u16* out = which == 0 ? oq : which == 1 ? ok : which == 2 ? ov : oo;
  const float s = which == 0 ? QSCALE : 1.0f;
  int i = blockIdx.x * 256 + threadIdx.x;
  float4 v = ((const float4*)in)[i];
  u16x4 o;
  o.x = bfu(v.x * s); o.y = bfu(v.y * s); o.z = bfu(v.z * s); o.w = bfu(v.w * s);
  ((u16x4*)out)[i] = o;
}

// ---------------- fused QKV GEMM (2-phase pipelined) ----------------
__global__ __launch_bounds__(256, 3) void gemm_qkv(const u16* __restrict__ A,
                                                   const u16* __restrict__ wq,
                                                   const u16* __restrict__ wk,
                                                   const u16* __restrict__ wv,
                                                   const float* __restrict__ bq,
                                                   const float* __restrict__ bk,
                                                   const float* __restrict__ bv,
                                                   u16* __restrict__ Qb,
                                                   u16* __restrict__ Kb,
                                                   u16* __restrict__ Vtb) {
  __shared__ u16 As[2][128 * 32];
  __shared__ u16 Bs[2][128 * 32];
  const int which = blockIdx.x >> 3;          // 0=Q 1=K 2=V
  const int col0 = (blockIdx.x & 7) * 128;
  const u16* W = which == 0 ? wq : which == 1 ? wk : wv;
  const float* bias = which == 0 ? bq : which == 1 ? bk : bv;
  const float bscale = which == 0 ? QSCALE : 1.0f;

  const int t = threadIdx.x, lane = t & 63, w = t >> 6;
  const int row0 = blockIdx.y * 128;
  const int wr = w >> 1, wc = w & 1;
  const int lr = lane & 15, lk = lane >> 4;

  f32x4 acc[4][4] = {};

  // stage K-step k0 into buffer bu (4 gl_lds per wave)
  auto stage = [&](int k0, int bu) {
#pragma unroll
    for (int i = 0; i < 2; ++i) {
      const int bc = i * 256 + w * 64;
      const int f = bc + lane;
      gl_lds16(A + (size_t)(row0 + (f >> 2)) * DIM + k0 + (f & 3) * 8, &As[bu][bc * 8]);
      gl_lds16(W + (size_t)(col0 + (f >> 2)) * DIM + k0 + (f & 3) * 8, &Bs[bu][bc * 8]);
    }
  };

  stage(0, 0);
  int buf = 0;
  for (int k0 = 0; k0 < DIM; k0 += 32) {
    if (k0 + 32 < DIM) { stage(k0 + 32, buf ^ 1); S_WAITCNT_VM(4); }
    else               { S_WAITCNT_VM(0); }
    S_BARRIER();  // this tile's data visible to all waves

    bf16x8 a[4], b[4];
#pragma unroll
    for (int m = 0; m < 4; ++m)
      a[m] = *(const bf16x8*)&As[buf][(wr * 64 + m * 16 + lr) * 32 + lk * 8];
#pragma unroll
    for (int n = 0; n < 4; ++n)
      b[n] = *(const bf16x8*)&Bs[buf][(wc * 64 + n * 16 + lr) * 32 + lk * 8];
    __builtin_amdgcn_s_setprio(1);
#pragma unroll
    for (int m = 0; m < 4; ++m)
#pragma unroll
      for (int n = 0; n < 4; ++n)
        acc[m][n] = mfma_bf16(a[m], b[n], acc[m][n]);
    __builtin_amdgcn_s_setprio(0);

    S_BARRIER();  // everyone done reading buf before it's restaged
    buf ^= 1;
  }

#pragma unroll
  for (int m = 0; m < 4; ++m) {
    const int rowb = row0 + wr * 64 + m * 16 + lk * 4;
#pragma unroll
    for (int n = 0; n < 4; ++n) {
      const int ocol = col0 + wc * 64 + n * 16 + lr;
      const float bc = bias[ocol] * bscale;
#pragma unroll
      for (int r = 0; r < 4; ++r) {
        const int rr = rowb + r;
        const float v = acc[m][n][r] + bc;
        if (which == 0) {
          Qb[(size_t)rr * DIM + ocol] = bfu(v);
        } else if (which == 1) {
          Kb[(size_t)rr * DIM + ocol] = bfu(v);
        } else {
          const size_t idx = ((((size_t)(rr >> 11) * NH + (ocol >> 6)) * HD + (ocol & 63)) << 11) + (rr & 2047);
          Vtb[idx] = bfu(v);
        }
      }
    }
  }
}

// ---------------- output projection GEMM (fp32 out, 2-phase) ----------------
__global__ __launch_bounds__(256, 3) void gemm_out(const u16* __restrict__ A,
                                                   const u16* __restrict__ W,
                                                   const float* __restrict__ bias,
                                                   float* __restrict__ C) {
  __shared__ u16 As[2][128 * 32];
  __shared__ u16 Bs[2][128 * 32];
  const int t = threadIdx.x, lane = t & 63, w = t >> 6;
  const int row0 = blockIdx.y * 128, col0 = blockIdx.x * 128;
  const int wr = w >> 1, wc = w & 1;
  const int lr = lane & 15, lk = lane >> 4;

  f32x4 acc[4][4] = {};

  auto stage = [&](int k0, int bu) {
#pragma unroll
    for (int i = 0; i < 2; ++i) {
      const int bc = i * 256 + w * 64;
      const int f = bc + lane;
      gl_lds16(A + (size_t)(row0 + (f >> 2)) * DIM + k0 + (f & 3) * 8, &As[bu][bc * 8]);
      gl_lds16(W + (size_t)(col0 + (f >> 2)) * DIM + k0 + (f & 3) * 8, &Bs[bu][bc * 8]);
    }
  };

  stage(0, 0);
  int buf = 0;
  for (int k0 = 0; k0 < DIM; k0 += 32) {
    if (k0 + 32 < DIM) { stage(k0 + 32, buf ^ 1); S_WAITCNT_VM(4); }
    else               { S_WAITCNT_VM(0); }
    S_BARRIER();

    bf16x8 a[4], b[4];
#pragma unroll
    for (int m = 0; m < 4; ++m)
      a[m] = *(const bf16x8*)&As[buf][(wr * 64 + m * 16 + lr) * 32 + lk * 8];
#pragma unroll
    for (int n = 0; n < 4; ++n)
      b[n] = *(const bf16x8*)&Bs[buf][(wc * 64 + n * 16 + lr) * 32 + lk * 8];
    __builtin_amdgcn_s_setprio(1);
#pragma unroll
    for (int m = 0; m < 4; ++m)
#pragma unroll
      for (int n = 0; n < 4; ++n)
        acc[m][n] = mfma_bf16(a[m], b[n], acc[m][n]);
    __builtin_amdgcn_s_setprio(0);

    S_BARRIER();
    buf ^= 1;
  }

#pragma unroll
  for (int m = 0; m < 4; ++m) {
    const int rowb = row0 + wr * 64 + m * 16 + lk * 4;
#pragma unroll
    for (int n = 0; n < 4; ++n) {
      const int col = col0 + wc * 64 + n * 16 + lr;
      const float bc = bias[col];
#pragma unroll
      for (int r = 0; r < 4; ++r)
        C[(size_t)(rowb + r) * DIM + col] = acc[m][n][r] + bc;
    }
  }
}

// ---------------- flash attention ----------------
// grid (T/256, B*H); 512 thr = 8 waves; wave w owns q-rows [q0+w*32, +32).
// Swapped QK^T (S^T: col=q in-lane softmax). K/V double-buffered in LDS,
// staged by global_load_lds with pre-swizzled source columns (rule 21).
// 2-phase counted-vmcnt pipeline; defer-max; exp2 (scale folded into Q).
__global__ __launch_bounds__(512, 2) void flash_attn(const u16* __restrict__ Q,
                                                     const u16* __restrict__ K,
                                                     const u16* __restrict__ Vt,
                                                     u16* __restrict__ O) {
  __shared__ u16 Ks[2][64 * 64];
  __shared__ u16 Vs[2][64 * 64];
  __shared__ u16 Ps[8][32][64];

  const int t = threadIdx.x, lane = t & 63, w = t >> 6;  // w: 0..7
  const int bh = blockIdx.y, b = bh >> 4, h = bh & 15;
  const int q0 = blockIdx.x * 256;
  const int lr = lane & 15, lk = lane >> 4;

  // Q B-frags (pre-scaled by log2e/8 via Wq/bq): col=q, k=d
  bf16x8 qf[2][2];
#pragma unroll
  for (int qm = 0; qm < 2; ++qm) {
    const size_t qrow = (size_t)(b * SEQ + q0 + w * 32 + qm * 16 + lr);
    qf[qm][0] = *(const bf16x8*)&Q[qrow * DIM + h * HD + lk * 8];
    qf[qm][1] = *(const bf16x8*)&Q[qrow * DIM + h * HD + lk * 8 + 32];
  }

  f32x4 o[2][4] = {};
  float m0[2] = {-INFINITY, -INFINITY}, l0[2] = {0.f, 0.f};

  // stage one 64-KV tile: 1 K + 1 V gl_lds per wave (8 waves cover 8KB each)
  auto stage = [&](int kt, int bu) {
    const int f = w * 64 + lane;          // 16B chunk id 0..511
    const int row = f >> 3, c = f & 7;
    const int cs = c ^ (row & 7);         // pre-swizzled source chunk
    gl_lds16(K + (size_t)(b * SEQ + kt + row) * DIM + h * HD + cs * 8, &Ks[bu][w * 512]);
    gl_lds16(Vt + (((size_t)bh * HD + row) << 11) + kt + cs * 8, &Vs[bu][w * 512]);
  };

  stage(0, 0);
  int buf = 0;
  for (int kt = 0; kt < SEQ; kt += 64) {
    if (kt + 64 < SEQ) { stage(kt + 64, buf ^ 1); S_WAITCNT_VM(2); }
    else               { S_WAITCNT_VM(0); }
    S_BARRIER();  // current tile's K/V visible

    const u16* ks = Ks[buf];
    const u16* vs = Vs[buf];

    // S^T: q = qm*16+lr (col), k = n*16 + lk*4 + r (row); log2 units
    f32x4 s[2][4] = {};
    __builtin_amdgcn_s_setprio(1);
#pragma unroll
    for (int n = 0; n < 4; ++n) {
      const int row = n * 16 + lr;
#pragma unroll
      for (int kk = 0; kk < 2; ++kk) {
        bf16x8 kf = *(const bf16x8*)&ks[row * 64 + (((lk + kk * 4) ^ (row & 7)) * 8)];
        s[0][n] = mfma_bf16(kf, qf[0][kk], s[0][n]);
        s[1][n] = mfma_bf16(kf, qf[1][kk], s[1][n]);
      }
    }
    __builtin_amdgcn_s_setprio(0);

    // online softmax (base-2), defer-max with THR=8
#pragma unroll
    for (int qm = 0; qm < 2; ++qm) {
      f32x4 m4 = s[qm][0];
#pragma unroll
      for (int n = 1; n < 4; ++n) {
        m4[0] = fmaxf(m4[0], s[qm][n][0]); m4[1] = fmaxf(m4[1], s[qm][n][1]);
        m4[2] = fmaxf(m4[2], s[qm][n][2]); m4[3] = fmaxf(m4[3], s[qm][n][3]);
      }
      float mx = fmaxf(fmaxf(m4[0], m4[1]), fmaxf(m4[2], m4[3]));
      mx = fmaxf(mx, __shfl_xor(mx, 16));
      mx = fmaxf(mx, __shfl_xor(mx, 32));
      if (__any(mx > m0[qm] + 8.0f)) {  // rescale only when max grew a lot
        const float mnew = fmaxf(m0[qm], mx);
        const float alpha = exp2f(m0[qm] - mnew);
        m0[qm] = mnew;
        l0[qm] *= alpha;
#pragma unroll
        for (int r = 0; r < 4; ++r) {
          const float a_r = __shfl(alpha, lk * 4 + r);
#pragma unroll
          for (int nd = 0; nd < 4; ++nd) o[qm][nd][r] *= a_r;
        }
      }

      float p[4][4];
      float rs = 0.f;
#pragma unroll
      for (int n = 0; n < 4; ++n)
#pragma unroll
        for (int r = 0; r < 4; ++r) { p[n][r] = exp2f(s[qm][n][r] - m0[qm]); rs += p[n][r]; }
      rs += __shfl_xor(rs, 16);
      rs += __shfl_xor(rs, 32);
      l0[qm] += rs;

      // P -> LDS (per-wave private), packed b64, XOR-swizzled
      const int prow = qm * 16 + lr;
      const int rx = (lr & 7) << 3;
#pragma unroll
      for (int n = 0; n < 4; ++n) {
        u16x4 pk;
        pk.x = bfu(p[n][0]); pk.y = bfu(p[n][1]); pk.z = bfu(p[n][2]); pk.w = bfu(p[n][3]);
        *(u16x4*)&Ps[w][prow][(n * 16 + lk * 4) ^ rx] = pk;
      }
    }

    // PV
    __builtin_amdgcn_s_setprio(1);
#pragma unroll
    for (int kk = 0; kk < 2; ++kk) {
      const int rx = (lr & 7) << 3;
      bf16x8 pa0 = *(const bf16x8*)&Ps[w][lr][(kk * 32 + lk * 8) ^ rx];
      bf16x8 pa1 = *(const bf16x8*)&Ps[w][16 + lr][(kk * 32 + lk * 8) ^ rx];
#pragma unroll
      for (int nd = 0; nd < 4; ++nd) {
        const int vrow = nd * 16 + lr;
        bf16x8 vf = *(const bf16x8*)&vs[vrow * 64 + (((lk + kk * 4) ^ (vrow & 7)) * 8)];
        o[0][nd] = mfma_bf16(pa0, vf, o[0][nd]);
        o[1][nd] = mfma_bf16(pa1, vf, o[1][nd]);
      }
    }
    __builtin_amdgcn_s_setprio(0);

    S_BARRIER();  // done reading buf before its restage next iter
    buf ^= 1;
  }

  // epilogue: normalize (pull l from lane lk*4+r), write bf16 row-major
#pragma unroll
  for (int qm = 0; qm < 2; ++qm) {
#pragma unroll
    for (int r = 0; r < 4; ++r) {
      const float inv = 1.f / __shfl(l0[qm], lk * 4 + r);
      const size_t grow = (size_t)(b * SEQ + q0 + w * 32 + qm * 16 + lk * 4 + r);
#pragma unroll
      for (int nd = 0; nd < 4; ++nd)
        O[grow * DIM + h * HD + nd * 16 + lr] = bfu(o[qm][nd][r] * inv);
    }
  }
}

// ---------------- launch ----------------
extern "C" void kernel_launch(void* const* d_in, const int* in_sizes, int n_in,
                              void* d_out, int out_size, void* d_ws, size_t ws_size,
                              hipStream_t stream) {
  (void)in_sizes; (void)n_in; (void)out_size; (void)ws_size;
  const float* x  = (const float*)d_in[0];
  const float* Wq = (const float*)d_in[1];
  const float* bq = (const float*)d_in[2];
  const float* Wk = (const float*)d_in[3];
  const float* bk = (const float*)d_in[4];
  const float* Wv = (const float*)d_in[5];
  const float* bv = (const float*)d_in[6];
  const float* Wo = (const float*)d_in[7];
  const float* bo = (const float*)d_in[8];

  char* ws = (char*)d_ws;
  u16* xb  = (u16*)(ws + 0);         // 8MB
  u16* wqb = (u16*)(ws + 8388608);   // 2MB
  u16* wkb = (u16*)(ws + 10485760);  // 2MB
  u16* wvb = (u16*)(ws + 12582912);  // 2MB
  u16* wob = (u16*)(ws + 14680064);  // 2MB
  u16* Qb  = (u16*)(ws + 16777216);  // 8MB
  u16* Kb  = (u16*)(ws + 25165824);  // 8MB
  u16* Vtb = (u16*)(ws + 33554432);  // 8MB  (per-head transposed V)
  u16* Ob  = (u16*)(ws + 41943040);  // 8MB

  cvt_x<<<NROWS * DIM / 4 / 256, 256, 0, stream>>>(x, xb);
  cvt_w4<<<dim3(DIM * DIM / 4 / 256, 4), 256, 0, stream>>>(Wq, Wk, Wv, Wo, wqb, wkb, wvb, wob);

  gemm_qkv<<<dim3(24, NROWS / 128), 256, 0, stream>>>(xb, wqb, wkb, wvb, bq, bk, bv, Qb, Kb, Vtb);

  flash_attn<<<dim3(SEQ / 256, 2 * NH), 512, 0, stream>>>(Qb, Kb, Vtb, Ob);

  gemm_out<<<dim3(DIM / 128, NROWS / 128), 256, 0, stream>>>(Ob, wob, bo, (float*)d_out);
}

// Round 4
// 138.313 us; speedup vs baseline: 1.1413x; 1.1413x over previous
//
#include <hip/hip_runtime.h>

// MHA: x[2,2048,1024] fp32; Q/K/V/O projections (y = x@W.T + b), 16 heads x 64,
// softmax(QK^T/8)V, output projection. bf16 MFMA, fp32 accumulate.
// R4: flash occupancy fix — QB=64 blocks (4 waves), grid 1024 = 4 blocks/CU
// (16 waves/CU), XCD-pinned (b,h)->XCD mapping so each XCD's KV set fits L2.
// raw v_exp via builtin. GEMMs unchanged from R3.

#define DIM 1024
#define NH 16
#define HD 64
#define SEQ 2048
#define NROWS 4096  // B*T

typedef unsigned short u16;
typedef __bf16 bf16_t;
typedef bf16_t bf16x8 __attribute__((ext_vector_type(8)));
typedef float f32x4 __attribute__((ext_vector_type(4)));
typedef u16 u16x4 __attribute__((ext_vector_type(4)));

typedef const __attribute__((address_space(1))) void* gas_ptr;
typedef __attribute__((address_space(3))) void* las_ptr;

#define S_BARRIER() asm volatile("s_barrier" ::: "memory")
#define S_WAITCNT_VM(N) asm volatile("s_waitcnt vmcnt(" #N ")" ::: "memory")

__device__ __forceinline__ void gl_lds16(const void* g, void* lds_wave_base) {
  __builtin_amdgcn_global_load_lds((gas_ptr)g, (las_ptr)lds_wave_base, 16, 0, 0);
}

__device__ __forceinline__ f32x4 mfma_bf16(bf16x8 a, bf16x8 b, f32x4 c) {
  return __builtin_amdgcn_mfma_f32_16x16x32_bf16(a, b, c, 0, 0, 0);
}

__device__ __forceinline__ u16 bfu(float f) {
  bf16_t b = (bf16_t)f;  // fptrunc, RNE
  union { bf16_t b; u16 u; } cv; cv.b = b; return cv.u;
}

__device__ __forceinline__ float fexp2(float x) {
#if __has_builtin(__builtin_amdgcn_exp2f)
  return __builtin_amdgcn_exp2f(x);  // raw v_exp_f32
#else
  return exp2f(x);
#endif
}

#define QSCALE 0.18033688f  // log2(e)/8: folds both 1/sqrt(64) and exp->exp2

// ---------------- fp32 -> bf16 converts ----------------
__global__ void cvt_x(const float* __restrict__ in, u16* __restrict__ out) {
  int i = blockIdx.x * 256 + threadIdx.x;
  float4 v = ((const float4*)in)[i];
  u16x4 o;
  o.x = bfu(v.x); o.y = bfu(v.y); o.z = bfu(v.z); o.w = bfu(v.w);
  ((u16x4*)out)[i] = o;
}

// all four weights in one launch; Wq scaled by log2e/8 (folds QK^T scale + exp2)
__global__ void cvt_w4(const float* __restrict__ wq, const float* __restrict__ wk,
                       const float* __restrict__ wv, const float* __restrict__ wo,
                       u16* __restrict__ oq, u16* __restrict__ ok,
                       u16* __restrict__ ov, u16* __restrict__ oo) {
  const int which = blockIdx.y;
  const float* in = which == 0 ? wq : which == 1 ? wk : which == 2 ? wv : wo;
  u16* out = which == 0 ? oq : which == 1 ? ok : which == 2 ? ov : oo;
  const float s = which == 0 ? QSCALE : 1.0f;
  int i = blockIdx.x * 256 + threadIdx.x;
  float4 v = ((const float4*)in)[i];
  u16x4 o;
  o.x = bfu(v.x * s); o.y = bfu(v.y * s); o.z = bfu(v.z * s); o.w = bfu(v.w * s);
  ((u16x4*)out)[i] = o;
}

// ---------------- fused QKV GEMM (2-phase pipelined) ----------------
__global__ __launch_bounds__(256, 3) void gemm_qkv(const u16* __restrict__ A,
                                                   const u16* __restrict__ wq,
                                                   const u16* __restrict__ wk,
                                                   const u16* __restrict__ wv,
                                                   const float* __restrict__ bq,
                                                   const float* __restrict__ bk,
                                                   const float* __restrict__ bv,
                                                   u16* __restrict__ Qb,
                                                   u16* __restrict__ Kb,
                                                   u16* __restrict__ Vtb) {
  __shared__ u16 As[2][128 * 32];
  __shared__ u16 Bs[2][128 * 32];
  const int which = blockIdx.x >> 3;          // 0=Q 1=K 2=V
  const int col0 = (blockIdx.x & 7) * 128;
  const u16* W = which == 0 ? wq : which == 1 ? wk : wv;
  const float* bias = which == 0 ? bq : which == 1 ? bk : bv;
  const float bscale = which == 0 ? QSCALE : 1.0f;

  const int t = threadIdx.x, lane = t & 63, w = t >> 6;
  const int row0 = blockIdx.y * 128;
  const int wr = w >> 1, wc = w & 1;
  const int lr = lane & 15, lk = lane >> 4;

  f32x4 acc[4][4] = {};

  auto stage = [&](int k0, int bu) {
#pragma unroll
    for (int i = 0; i < 2; ++i) {
      const int bc = i * 256 + w * 64;
      const int f = bc + lane;
      gl_lds16(A + (size_t)(row0 + (f >> 2)) * DIM + k0 + (f & 3) * 8, &As[bu][bc * 8]);
      gl_lds16(W + (size_t)(col0 + (f >> 2)) * DIM + k0 + (f & 3) * 8, &Bs[bu][bc * 8]);
    }
  };

  stage(0, 0);
  int buf = 0;
  for (int k0 = 0; k0 < DIM; k0 += 32) {
    if (k0 + 32 < DIM) { stage(k0 + 32, buf ^ 1); S_WAITCNT_VM(4); }
    else               { S_WAITCNT_VM(0); }
    S_BARRIER();

    bf16x8 a[4], b[4];
#pragma unroll
    for (int m = 0; m < 4; ++m)
      a[m] = *(const bf16x8*)&As[buf][(wr * 64 + m * 16 + lr) * 32 + lk * 8];
#pragma unroll
    for (int n = 0; n < 4; ++n)
      b[n] = *(const bf16x8*)&Bs[buf][(wc * 64 + n * 16 + lr) * 32 + lk * 8];
    __builtin_amdgcn_s_setprio(1);
#pragma unroll
    for (int m = 0; m < 4; ++m)
#pragma unroll
      for (int n = 0; n < 4; ++n)
        acc[m][n] = mfma_bf16(a[m], b[n], acc[m][n]);
    __builtin_amdgcn_s_setprio(0);

    S_BARRIER();
    buf ^= 1;
  }

#pragma unroll
  for (int m = 0; m < 4; ++m) {
    const int rowb = row0 + wr * 64 + m * 16 + lk * 4;
#pragma unroll
    for (int n = 0; n < 4; ++n) {
      const int ocol = col0 + wc * 64 + n * 16 + lr;
      const float bc = bias[ocol] * bscale;
#pragma unroll
      for (int r = 0; r < 4; ++r) {
        const int rr = rowb + r;
        const float v = acc[m][n][r] + bc;
        if (which == 0) {
          Qb[(size_t)rr * DIM + ocol] = bfu(v);
        } else if (which == 1) {
          Kb[(size_t)rr * DIM + ocol] = bfu(v);
        } else {
          const size_t idx = ((((size_t)(rr >> 11) * NH + (ocol >> 6)) * HD + (ocol & 63)) << 11) + (rr & 2047);
          Vtb[idx] = bfu(v);
        }
      }
    }
  }
}

// ---------------- output projection GEMM (fp32 out, 2-phase) ----------------
__global__ __launch_bounds__(256, 3) void gemm_out(const u16* __restrict__ A,
                                                   const u16* __restrict__ W,
                                                   const float* __restrict__ bias,
                                                   float* __restrict__ C) {
  __shared__ u16 As[2][128 * 32];
  __shared__ u16 Bs[2][128 * 32];
  const int t = threadIdx.x, lane = t & 63, w = t >> 6;
  const int row0 = blockIdx.y * 128, col0 = blockIdx.x * 128;
  const int wr = w >> 1, wc = w & 1;
  const int lr = lane & 15, lk = lane >> 4;

  f32x4 acc[4][4] = {};

  auto stage = [&](int k0, int bu) {
#pragma unroll
    for (int i = 0; i < 2; ++i) {
      const int bc = i * 256 + w * 64;
      const int f = bc + lane;
      gl_lds16(A + (size_t)(row0 + (f >> 2)) * DIM + k0 + (f & 3) * 8, &As[bu][bc * 8]);
      gl_lds16(W + (size_t)(col0 + (f >> 2)) * DIM + k0 + (f & 3) * 8, &Bs[bu][bc * 8]);
    }
  };

  stage(0, 0);
  int buf = 0;
  for (int k0 = 0; k0 < DIM; k0 += 32) {
    if (k0 + 32 < DIM) { stage(k0 + 32, buf ^ 1); S_WAITCNT_VM(4); }
    else               { S_WAITCNT_VM(0); }
    S_BARRIER();

    bf16x8 a[4], b[4];
#pragma unroll
    for (int m = 0; m < 4; ++m)
      a[m] = *(const bf16x8*)&As[buf][(wr * 64 + m * 16 + lr) * 32 + lk * 8];
#pragma unroll
    for (int n = 0; n < 4; ++n)
      b[n] = *(const bf16x8*)&Bs[buf][(wc * 64 + n * 16 + lr) * 32 + lk * 8];
    __builtin_amdgcn_s_setprio(1);
#pragma unroll
    for (int m = 0; m < 4; ++m)
#pragma unroll
      for (int n = 0; n < 4; ++n)
        acc[m][n] = mfma_bf16(a[m], b[n], acc[m][n]);
    __builtin_amdgcn_s_setprio(0);

    S_BARRIER();
    buf ^= 1;
  }

#pragma unroll
  for (int m = 0; m < 4; ++m) {
    const int rowb = row0 + wr * 64 + m * 16 + lk * 4;
#pragma unroll
    for (int n = 0; n < 4; ++n) {
      const int col = col0 + wc * 64 + n * 16 + lr;
      const float bc = bias[col];
#pragma unroll
      for (int r = 0; r < 4; ++r)
        C[(size_t)(rowb + r) * DIM + col] = acc[m][n][r] + bc;
    }
  }
}

// ---------------- flash attention ----------------
// 1-D grid of 1024 blocks, 256 thr = 4 waves; wave w owns q-rows [q0+w*16,+16).
// Block id L -> (bh, qt) with L%8 == bh%8 so all 32 q-tiles of one (b,h) land
// on one XCD (round-robin model): per-XCD live KV = 4 heads x 512KB = 2MB < L2.
// Swapped QK^T (S^T: col=q, in-lane softmax, 2 shuffles). K/V double-buffered,
// counted-vmcnt pipeline, defer-max, exp2 with scale folded into Q.
__global__ __launch_bounds__(256, 4) void flash_attn(const u16* __restrict__ Q,
                                                     const u16* __restrict__ K,
                                                     const u16* __restrict__ Vt,
                                                     u16* __restrict__ O) {
  __shared__ u16 Ks[2][64 * 64];
  __shared__ u16 Vs[2][64 * 64];
  __shared__ u16 Ps[4][16][64];

  const int t = threadIdx.x, lane = t & 63, w = t >> 6;  // w: 0..3
  const int L = blockIdx.x;
  const int bh = ((L >> 8) << 3) | (L & 7);  // 0..31, XCD-pinned
  const int qt = (L >> 3) & 31;
  const int b = bh >> 4, h = bh & 15;
  const int q0 = qt * 64;
  const int lr = lane & 15, lk = lane >> 4;

  // Q B-frags (pre-scaled by log2e/8 via Wq/bq): col=q, k=d
  const size_t qrow = (size_t)(b * SEQ + q0 + w * 16 + lr);
  bf16x8 qf[2];
  qf[0] = *(const bf16x8*)&Q[qrow * DIM + h * HD + lk * 8];
  qf[1] = *(const bf16x8*)&Q[qrow * DIM + h * HD + lk * 8 + 32];

  f32x4 o[4] = {};
  float m0 = -INFINITY, l0 = 0.f;

  // stage one 64x64 K tile + V tile; 4 waves x (2 K + 2 V) gl_lds
  auto stage = [&](int kt, int bu) {
#pragma unroll
    for (int i = 0; i < 2; ++i) {
      const int bc = i * 256 + w * 64;
      const int f = bc + lane;          // 16B chunk id 0..511
      const int row = f >> 3, c = f & 7;
      const int cs = c ^ (row & 7);     // pre-swizzled source chunk (rule 21)
      gl_lds16(K + (size_t)(b * SEQ + kt + row) * DIM + h * HD + cs * 8, &Ks[bu][bc * 8]);
      gl_lds16(Vt + (((size_t)bh * HD + row) << 11) + kt + cs * 8, &Vs[bu][bc * 8]);
    }
  };

  stage(0, 0);
  int buf = 0;
  for (int kt = 0; kt < SEQ; kt += 64) {
    if (kt + 64 < SEQ) { stage(kt + 64, buf ^ 1); S_WAITCNT_VM(4); }
    else               { S_WAITCNT_VM(0); }
    S_BARRIER();  // current tile's K/V visible

    const u16* ks = Ks[buf];
    const u16* vs = Vs[buf];

    // S^T: q = lr (col), k = n*16 + lk*4 + r (row); log2 units
    f32x4 s[4] = {};
    __builtin_amdgcn_s_setprio(1);
#pragma unroll
    for (int n = 0; n < 4; ++n) {
      const int row = n * 16 + lr;
#pragma unroll
      for (int kk = 0; kk < 2; ++kk) {
        bf16x8 kf = *(const bf16x8*)&ks[row * 64 + (((lk + kk * 4) ^ (row & 7)) * 8)];
        s[n] = mfma_bf16(kf, qf[kk], s[n]);
      }
    }
    __builtin_amdgcn_s_setprio(0);

    // online softmax (base-2), defer-max with THR=8
    f32x4 m4 = s[0];
#pragma unroll
    for (int n = 1; n < 4; ++n) {
      m4[0] = fmaxf(m4[0], s[n][0]); m4[1] = fmaxf(m4[1], s[n][1]);
      m4[2] = fmaxf(m4[2], s[n][2]); m4[3] = fmaxf(m4[3], s[n][3]);
    }
    float mx = fmaxf(fmaxf(m4[0], m4[1]), fmaxf(m4[2], m4[3]));
    mx = fmaxf(mx, __shfl_xor(mx, 16));
    mx = fmaxf(mx, __shfl_xor(mx, 32));
    if (__any(mx > m0 + 8.0f)) {  // rescale only when max grew a lot
      const float mnew = fmaxf(m0, mx);
      const float alpha = fexp2(m0 - mnew);
      m0 = mnew;
      l0 *= alpha;
#pragma unroll
      for (int r = 0; r < 4; ++r) {
        const float a_r = __shfl(alpha, lk * 4 + r);
#pragma unroll
        for (int nd = 0; nd < 4; ++nd) o[nd][r] *= a_r;
      }
    }

    float p[4][4];
    float rs = 0.f;
#pragma unroll
    for (int n = 0; n < 4; ++n)
#pragma unroll
      for (int r = 0; r < 4; ++r) { p[n][r] = fexp2(s[n][r] - m0); rs += p[n][r]; }
    rs += __shfl_xor(rs, 16);
    rs += __shfl_xor(rs, 32);
    l0 += rs;

    // P -> LDS (per-wave private), packed b64, XOR-swizzled
    const int rx = (lr & 7) << 3;
#pragma unroll
    for (int n = 0; n < 4; ++n) {
      u16x4 pk;
      pk.x = bfu(p[n][0]); pk.y = bfu(p[n][1]); pk.z = bfu(p[n][2]); pk.w = bfu(p[n][3]);
      *(u16x4*)&Ps[w][lr][(n * 16 + lk * 4) ^ rx] = pk;
    }

    // PV
    __builtin_amdgcn_s_setprio(1);
#pragma unroll
    for (int kk = 0; kk < 2; ++kk) {
      bf16x8 pa = *(const bf16x8*)&Ps[w][lr][(kk * 32 + lk * 8) ^ rx];
#pragma unroll
      for (int nd = 0; nd < 4; ++nd) {
        const int vrow = nd * 16 + lr;
        bf16x8 vf = *(const bf16x8*)&vs[vrow * 64 + (((lk + kk * 4) ^ (vrow & 7)) * 8)];
        o[nd] = mfma_bf16(pa, vf, o[nd]);
      }
    }
    __builtin_amdgcn_s_setprio(0);

    S_BARRIER();  // done reading buf before its restage next iter
    buf ^= 1;
  }

  // epilogue: normalize (pull l from lane lk*4+r), write bf16 row-major
#pragma unroll
  for (int r = 0; r < 4; ++r) {
    const float inv = 1.f / __shfl(l0, lk * 4 + r);
    const size_t grow = (size_t)(b * SEQ + q0 + w * 16 + lk * 4 + r);
#pragma unroll
    for (int nd = 0; nd < 4; ++nd)
      O[grow * DIM + h * HD + nd * 16 + lr] = bfu(o[nd][r] * inv);
  }
}

// ---------------- launch ----------------
extern "C" void kernel_launch(void* const* d_in, const int* in_sizes, int n_in,
                              void* d_out, int out_size, void* d_ws, size_t ws_size,
                              hipStream_t stream) {
  (void)in_sizes; (void)n_in; (void)out_size; (void)ws_size;
  const float* x  = (const float*)d_in[0];
  const float* Wq = (const float*)d_in[1];
  const float* bq = (const float*)d_in[2];
  const float* Wk = (const float*)d_in[3];
  const float* bk = (const float*)d_in[4];
  const float* Wv = (const float*)d_in[5];
  const float* bv = (const float*)d_in[6];
  const float* Wo = (const float*)d_in[7];
  const float* bo = (const float*)d_in[8];

  char* ws = (char*)d_ws;
  u16* xb  = (u16*)(ws + 0);         // 8MB
  u16* wqb = (u16*)(ws + 8388608);   // 2MB
  u16* wkb = (u16*)(ws + 10485760);  // 2MB
  u16* wvb = (u16*)(ws + 12582912);  // 2MB
  u16* wob = (u16*)(ws + 14680064);  // 2MB
  u16* Qb  = (u16*)(ws + 16777216);  // 8MB
  u16* Kb  = (u16*)(ws + 25165824);  // 8MB
  u16* Vtb = (u16*)(ws + 33554432);  // 8MB  (per-head transposed V)
  u16* Ob  = (u16*)(ws + 41943040);  // 8MB

  cvt_x<<<NROWS * DIM / 4 / 256, 256, 0, stream>>>(x, xb);
  cvt_w4<<<dim3(DIM * DIM / 4 / 256, 4), 256, 0, stream>>>(Wq, Wk, Wv, Wo, wqb, wkb, wvb, wob);

  gemm_qkv<<<dim3(24, NROWS / 128), 256, 0, stream>>>(xb, wqb, wkb, wvb, bq, bk, bv, Qb, Kb, Vtb);

  flash_attn<<<1024, 256, 0, stream>>>(Qb, Kb, Vtb, Ob);

  gemm_out<<<dim3(DIM / 128, NROWS / 128), 256, 0, stream>>>(Ob, wob, bo, (float*)d_out);
}